// Round 1
// baseline (970.131 us; speedup 1.0000x reference)
//
#include <hip/hip_runtime.h>
#include <math.h>

#define TPB 256

__global__ __launch_bounds__(TPB) void e8k(
    const float* __restrict__ g_obs,
    const float* __restrict__ pw1, const float* __restrict__ pb1,
    const float* __restrict__ pw2, const float* __restrict__ pb2,
    const float* __restrict__ lemb,
    const float* __restrict__ bcp,
    const float* __restrict__ rcpar,
    const float* __restrict__ bcx,
    const float* __restrict__ glogdecay,
    const float* __restrict__ rw1, const float* __restrict__ rb1,
    const float* __restrict__ rw2, const float* __restrict__ rb2,
    const float* __restrict__ rgate,
    float* __restrict__ out, int B)
{
    __shared__ float smem[TPB*42];
    const int tid = threadIdx.x;
    const int row = blockIdx.x*TPB + tid;

    // ---- coalesced obs staging ----
    {
        const size_t base = (size_t)blockIdx.x*TPB*14;
        const size_t lim  = (size_t)B*14;
        for (int t = tid; t < TPB*14; t += TPB){
            size_t g = base + (size_t)t;
            smem[t] = (g < lim) ? g_obs[g] : 0.f;
        }
    }
    __syncthreads();
    const bool active = row < B;

    double q[8];
    double residual[8];
    int i1=0,i2=0,i3=0,i4=0,i5=0,i6=0,i7=0;
    double decay = 1.0;

    if (active) {
        // ---- projection MLP (f64 for argmin exactness) ----
        double ob[14];
        #pragma unroll
        for (int j=0;j<14;j++) ob[j] = (double)smem[tid*14+j];
        double qa[8];
        #pragma unroll
        for (int m=0;m<8;m++) qa[m] = (double)pb2[m];
        for (int k=0;k<32;k++){            // rolled: single erf instantiation
            double a = (double)pb1[k];
            #pragma unroll
            for (int j=0;j<14;j++) a += (double)pw1[k*14+j]*ob[j];
            double hk = 0.5*a*(1.0 + erf(a*0.70710678118654752440));
            #pragma unroll
            for (int m=0;m<8;m++) qa[m] += (double)pw2[m*32+k]*hk;
        }
        double n2 = 0.0;
        #pragma unroll
        for (int m=0;m<8;m++) n2 += qa[m]*qa[m];
        double nr = sqrt(n2); if (nr < 1e-12) nr = 1e-12;
        const double SQ2 = 1.4142135623730951;
        #pragma unroll
        for (int m=0;m<8;m++){ q[m] = qa[m]/nr*SQ2; residual[m]=q[m]; }

        decay = exp((double)glogdecay[0]);
        double dpow = 1.0;

        // ---- residual E8 quantization chain ----
        for (int lvl=0; lvl<8; ++lvl){
            double scale = 2.0/dpow;
            double x[8];
            #pragma unroll
            for (int k=0;k<8;k++) x[k] = residual[k]/scale;
            double x2 = 0.0;
            #pragma unroll
            for (int k=0;k<8;k++) x2 += x[k]*x[k];
            double c = x2 + 2.0;          // r2 == 2 exactly for every E8 root
            double best = 1e300; int bidx = 0;

            // 112 pair roots (+-1,+-1,0^6): dots are +-x_i +- x_j
            #pragma unroll
            for (int i=0;i<8;i++){
                #pragma unroll
                for (int j=i+1;j<8;j++){
                    const int pb = 4*(7*i - (i*(i-1))/2 + (j-i-1));
                    double p2 = 2.0*(x[i]+x[j]);
                    double m2 = 2.0*(x[i]-x[j]);
                    double d;
                    d = c - p2; if (d<best){best=d;bidx=pb;  }
                    d = c - m2; if (d<best){best=d;bidx=pb+1;}
                    d = c + m2; if (d<best){best=d;bidx=pb+2;}
                    d = c + p2; if (d<best){best=d;bidx=pb+3;}
                }
            }
            // 128 half roots (+-1/2)^8, even parity: 2*dot = lo16[b&15]+hi16[b>>4]
            {
                double e01p=x[0]+x[1], e01m=x[0]-x[1];
                double e23p=x[2]+x[3], e23m=x[2]-x[3];
                double e45p=x[4]+x[5], e45m=x[4]-x[5];
                double e67p=x[6]+x[7], e67m=x[6]-x[7];
                double s01[4]={e01p,-e01m,e01m,-e01p};
                double s23[4]={e23p,-e23m,e23m,-e23p};
                double s45[4]={e45p,-e45m,e45m,-e45p};
                double s67[4]={e67p,-e67m,e67m,-e67p};
                double lo16[16], hi16[16];
                #pragma unroll
                for (int p=0;p<16;p++){
                    lo16[p] = s01[p&3] + s23[(p>>2)&3];
                    hi16[p] = s45[p&3] + s67[(p>>2)&3];
                }
                #pragma unroll
                for (int b=0;b<256;b++){
                    if (__builtin_popcount(b)&1) continue;   // even parity only
                    double d = c - (lo16[b&15] + hi16[b>>4]);
                    const int kidx = 112 + (b>>1);
                    if (d<best){best=d;bidx=kidx;}
                }
            }
            // decode bidx -> root, update residual
            {
                int p = bidx>>2, s = bidx&3;
                int gi = (p>=7)+(p>=13)+(p>=18)+(p>=22)+(p>=25)+(p>=27);
                int basep = 0;
                basep = p>=7 ? 7 : basep;
                basep = p>=13? 13: basep;
                basep = p>=18? 18: basep;
                basep = p>=22? 22: basep;
                basep = p>=25? 25: basep;
                basep = p>=27? 27: basep;
                int gj = gi + 1 + (p - basep);
                double sI = (s&2)? -1.0:1.0;
                double sJ = (s&1)? -1.0:1.0;
                int hb = (bidx-112)<<1;
                hb |= (__builtin_popcount(hb)&1);  // restore even parity -> bits
                bool isPair = bidx < 112;
                #pragma unroll
                for (int k=0;k<8;k++){
                    double cp = ((k==gi)? sI:0.0) + ((k==gj)? sJ:0.0);
                    double ch = ((hb>>k)&1)? -0.5:0.5;
                    double coef = isPair? cp : ch;
                    residual[k] -= coef*scale;
                }
            }
            if      (lvl==1) i1=bidx;
            else if (lvl==2) i2=bidx;
            else if (lvl==3) i3=bidx;
            else if (lvl==4) i4=bidx;
            else if (lvl==5) i5=bidx;
            else if (lvl==6) i6=bidx;
            else if (lvl==7) i7=bidx;
            dpow *= decay;
        }
    }

    __syncthreads();   // everyone done with obs region of smem; reuse for tables
    if (!active) return;

    // ---- per-thread dot tables in LDS (stride 41: conflict-free) ----
    float* T = smem + tid*41;
    float qf[8];
    #pragma unroll
    for (int k=0;k<8;k++){ qf[k]=(float)q[k]; T[k]=qf[k]; }
    {
        float a01p=qf[0]+qf[1], a01m=qf[0]-qf[1];
        float a23p=qf[2]+qf[3], a23m=qf[2]-qf[3];
        float a45p=qf[4]+qf[5], a45m=qf[4]-qf[5];
        float a67p=qf[6]+qf[7], a67m=qf[6]-qf[7];
        float s01[4]={a01p,-a01m,a01m,-a01p};
        float s23[4]={a23p,-a23m,a23m,-a23p};
        float s45[4]={a45p,-a45m,a45m,-a45p};
        float s67[4]={a67p,-a67m,a67m,-a67p};
        #pragma unroll
        for (int p=0;p<16;p++){
            T[8+p]  = s01[p&3]+s23[(p>>2)&3];
            T[24+p] = s45[p&3]+s67[(p>>2)&3];
        }
    }

    // ---- fused softmax + weighted sums (level 0) ----
    float emb[52], ctl[4];
    #pragma unroll
    for (int k=0;k<52;k++) emb[k]=0.f;
    ctl[0]=ctl[1]=ctl[2]=ctl[3]=0.f;
    float den = 0.f;
    const float IS2   = 0.70710678f;          // 1/sqrt2  (|roots|=sqrt2)
    const float HS2   = 0.35355339f;          // 0.5/sqrt2
    const float LOG2F = 0.69314718056f;
    auto proc = [&](float sims, int j){
        float lg = sims - bcx[j]*LOG2F;       // logits bounded in [-sqrt2,sqrt2]; exp safe
        float e = __expf(lg);
        den += e;
        const float* ep = lemb + j*52;        // wave-uniform j -> scalar loads
        #pragma unroll
        for (int k=0;k<52;k++) emb[k] = fmaf(e, ep[k], emb[k]);
        const float* cq = bcp + j*4;
        #pragma unroll
        for (int k=0;k<4;k++) ctl[k] = fmaf(e, cq[k], ctl[k]);
    };
    {
        int ii=0, jn=1;
        for (int pc=0; pc<28; ++pc){
            float a = T[ii], b = T[jn];
            float p = a+b, m = a-b;
            proc( p*IS2, 4*pc+0);
            proc( m*IS2, 4*pc+1);
            proc(-m*IS2, 4*pc+2);
            proc(-p*IS2, 4*pc+3);
            if (++jn == 8){ ++ii; jn = ii+1; }
        }
        for (int b=0;b<256;b++){
            if (__builtin_popcount(b)&1) continue;
            float dot2 = T[8+(b&15)] + T[24+(b>>4)];
            proc(dot2*HS2, 112+(b>>1));
        }
    }
    float rden = 1.0f/den;
    #pragma unroll
    for (int k=0;k<52;k++) emb[k] *= rden;
    #pragma unroll
    for (int k=0;k<4;k++) ctl[k] *= rden;

    // ---- hard-index gathers, levels 1..7 ----
    {
        double dp = decay;
        const float* ep; const float* cq; float ild;
        #define DO_G(LVL, IV) \
            ild = (float)(1.0/dp); \
            ep = lemb + ((size_t)(LVL)*240 + (size_t)(IV))*52; \
            cq = rcpar + ((size_t)((LVL)-1)*240 + (size_t)(IV))*4; \
            _Pragma("unroll") \
            for (int k=0;k<52;k++) emb[k] = fmaf(ild, ep[k], emb[k]); \
            _Pragma("unroll") \
            for (int k=0;k<4;k++) ctl[k] = fmaf(ild, cq[k], ctl[k]); \
            dp *= decay;
        DO_G(1,i1) DO_G(2,i2) DO_G(3,i3) DO_G(4,i4) DO_G(5,i5) DO_G(6,i6) DO_G(7,i7)
        #undef DO_G
    }

    // ---- gated refinement MLP ----
    float rf[52];
    #pragma unroll
    for (int m=0;m<52;m++) rf[m] = rb2[m];
    for (int k=0;k<52;k++){                 // rolled: single erff instantiation
        float a = rb1[k];
        #pragma unroll
        for (int j=0;j<52;j++) a = fmaf(rw1[k*52+j], emb[j], a);
        float t = 0.5f*a*(1.f+erff(a*0.70710678f));
        #pragma unroll
        for (int m=0;m<52;m++) rf[m] = fmaf(t, rw2[m*52+k], rf[m]);
    }
    float sg;
    {
        float g = rgate[0];
        sg = 1.f/(1.f+__expf(-g));
    }
    #pragma unroll
    for (int m=0;m<52;m++) emb[m] = fmaf(sg, rf[m], emb[m]);

    // ---- store [emb(52) | ctl(4)] as 14 float4 ----
    float* orow = out + (size_t)row*56;
    float4* o4 = (float4*)orow;
    #pragma unroll
    for (int t=0;t<13;t++)
        o4[t] = make_float4(emb[4*t], emb[4*t+1], emb[4*t+2], emb[4*t+3]);
    o4[13] = make_float4(ctl[0], ctl[1], ctl[2], ctl[3]);
}

extern "C" void kernel_launch(void* const* d_in, const int* in_sizes, int n_in,
                              void* d_out, int out_size, void* d_ws, size_t ws_size,
                              hipStream_t stream)
{
    const float* obs  = (const float*)d_in[0];
    const float* pw1  = (const float*)d_in[1];
    const float* pb1  = (const float*)d_in[2];
    const float* pw2  = (const float*)d_in[3];
    const float* pb2  = (const float*)d_in[4];
    const float* lemb = (const float*)d_in[5];
    const float* bcp  = (const float*)d_in[6];
    const float* rcp  = (const float*)d_in[7];
    const float* bcx  = (const float*)d_in[8];
    const float* ld   = (const float*)d_in[9];
    const float* rw1  = (const float*)d_in[10];
    const float* rb1  = (const float*)d_in[11];
    const float* rw2  = (const float*)d_in[12];
    const float* rb2  = (const float*)d_in[13];
    const float* rg   = (const float*)d_in[14];

    int B = in_sizes[0] / 14;
    int grid = (B + TPB - 1) / TPB;
    e8k<<<grid, TPB, 0, stream>>>(obs, pw1, pb1, pw2, pb2, lemb, bcp, rcp, bcx, ld,
                                  rw1, rb1, rw2, rb2, rg, (float*)d_out, B);
}